// Round 9
// baseline (166.675 us; speedup 1.0000x reference)
//
#include <hip/hip_runtime.h>

typedef unsigned short u16;
typedef __attribute__((ext_vector_type(8))) short bf16x8;   // MFMA A/B frag (8 bf16)
typedef __attribute__((ext_vector_type(8))) unsigned short u16x8;
typedef __attribute__((ext_vector_type(4))) float f32x4;    // MFMA C/D frag

#define MFMA16(a, b, c) __builtin_amdgcn_mfma_f32_16x16x32_bf16((a), (b), (c), 0, 0, 0)

// async global->LDS, 16B per lane; LDS dest = wave-uniform base + lane*16
__device__ __forceinline__ void gll16(const void* g, void* l) {
    __builtin_amdgcn_global_load_lds(
        (const __attribute__((address_space(1))) unsigned int*)g,
        (__attribute__((address_space(3))) unsigned int*)l, 16, 0, 0);
}

__device__ __forceinline__ u16 f2b(float f) {   // f32 -> bf16 RNE (scalar)
    unsigned int u = __float_as_uint(f);
    u += 0x7fffu + ((u >> 16) & 1u);
    return (u16)(u >> 16);
}

__device__ __forceinline__ unsigned int pkbf(float a, float b) {  // packed bf16x2
    return (unsigned int)f2b(a) | ((unsigned int)f2b(b) << 16);
}

// ---------------------------------------------------------------- one cast kernel
// blocks 0..2047: x (4M f32). blocks 2048..4095: the four 1M-element weights.
__global__ __launch_bounds__(256) void cast_all(const float* __restrict__ x,
                                                const float* __restrict__ w0,
                                                const float* __restrict__ w1,
                                                const float* __restrict__ w2,
                                                const float* __restrict__ w3,
                                                u16* __restrict__ xb,
                                                u16* __restrict__ wb) {
    const int bid = blockIdx.x;
    const float* s; u16* d; int off;
    if (bid < 2048) { s = x; d = xb; off = bid; }
    else {
        const int wi = (bid - 2048) >> 9;
        s = (wi == 0) ? w0 : (wi == 1) ? w1 : (wi == 2) ? w2 : w3;
        d = wb + (size_t)wi * 1048576;
        off = (bid - 2048) & 511;
    }
    const int i = (off * 256 + threadIdx.x) * 8;
    float4 a = *(const float4*)(s + i);
    float4 b = *(const float4*)(s + i + 4);
    *(uint4*)(d + i) = make_uint4(pkbf(a.x, a.y), pkbf(a.z, a.w),
                                  pkbf(b.x, b.y), pkbf(b.z, b.w));
}

// ---------------------------------------------------------------- GEMM, dbuf K-loop
// Y = A[M,K] @ W[rows,K]^T, bf16 in, fp32 acc, BMxBN tile, BK=32, 4 waves (2x2),
// LDS double-buffered: ONE barrier per iter, prefetch for k+1 issued right after
// the barrier so its latency is hidden behind this iter's compute.
// MODE 0: f32 out, stride ldY. MODE 1 (BM=BN=128): fused QKV epilogue — cols<2048
// -> bf16 qk (stride 2048); cols>=2048 (V proj) -> transposed into vT.
template <int BM, int BN, int MODE>
__global__ __launch_bounds__(256) void gemm_bt(const u16* __restrict__ A,
                                               const u16* __restrict__ W,
                                               void* __restrict__ Yv,
                                               u16* __restrict__ vT,
                                               int K, int ldY) {
    constexpr int MI = BM / 32, NJ = BN / 32;      // frags per wave
    constexpr int ACH = BM / 16;                   // A staging chunks (1KB each)
    constexpr int NPW = (BM + BN) / 64;            // chunks per wave
    __shared__ u16 As[2][BM * 32];
    __shared__ u16 Bs[2][BN * 32];
    const int t = threadIdx.x, w = t >> 6, lane = t & 63;
    const int quad = lane >> 4, m16 = lane & 15;
    const int wr = (w >> 1) * (BM / 2), wc = (w & 1) * (BN / 2);
    const int row0 = blockIdx.x * BM, col0 = blockIdx.y * BN;
    const int srow = lane >> 2, scol = (lane & 3) * 8;

    auto stage = [&](int buf, int k0) {
#pragma unroll
        for (int cc = 0; cc < NPW; ++cc) {
            const int c = w * NPW + cc;
            if (c < ACH)
                gll16(A + (size_t)(row0 + c * 16 + srow) * K + k0 + scol,
                      &As[buf][c * 512]);
            else
                gll16(W + (size_t)(col0 + (c - ACH) * 16 + srow) * K + k0 + scol,
                      &Bs[buf][(c - ACH) * 512]);
        }
    };

    f32x4 acc[MI][NJ];
#pragma unroll
    for (int i = 0; i < MI; ++i)
#pragma unroll
        for (int j = 0; j < NJ; ++j) acc[i][j] = (f32x4){0.f, 0.f, 0.f, 0.f};

    stage(0, 0);
    for (int k0 = 0; k0 < K; k0 += 32) {
        const int buf = (k0 >> 5) & 1;
        __syncthreads();                       // tile k0 landed; buf^1 free
        if (k0 + 32 < K) stage(buf ^ 1, k0 + 32);   // hidden behind compute
        bf16x8 af[MI], bf[NJ];
#pragma unroll
        for (int i = 0; i < MI; ++i)
            af[i] = *(const bf16x8*)&As[buf][(wr + i * 16 + m16) * 32 + quad * 8];
#pragma unroll
        for (int j = 0; j < NJ; ++j)
            bf[j] = *(const bf16x8*)&Bs[buf][(wc + j * 16 + m16) * 32 + quad * 8];
#pragma unroll
        for (int i = 0; i < MI; ++i)
#pragma unroll
            for (int j = 0; j < NJ; ++j) acc[i][j] = MFMA16(af[i], bf[j], acc[i][j]);
    }
    // epilogue: D[row=quad*4+r][col=m16] per 16x16 tile
    if constexpr (MODE == 0) {
#pragma unroll
        for (int i = 0; i < MI; ++i)
#pragma unroll
            for (int j = 0; j < NJ; ++j)
#pragma unroll
                for (int r = 0; r < 4; ++r)
                    ((float*)Yv)[(size_t)(row0 + wr + i * 16 + quad * 4 + r) * ldY +
                                 col0 + wc + j * 16 + m16] = acc[i][j][r];
    } else {
        if (col0 < 2048) {              // Q/K projection -> bf16, stride 2048
            u16* qk = (u16*)Yv;
#pragma unroll
            for (int i = 0; i < MI; ++i)
#pragma unroll
                for (int j = 0; j < NJ; ++j)
#pragma unroll
                    for (int r = 0; r < 4; ++r)
                        qk[(size_t)(row0 + wr + i * 16 + quad * 4 + r) * 2048 +
                           col0 + wc + j * 16 + m16] = f2b(acc[i][j][r]);
        } else {                        // V projection -> transposed vT
#pragma unroll
            for (int i = 0; i < MI; ++i) {
                const int rbase = row0 + wr + i * 16;
                const int bb = rbase >> 10;
                const int tok0 = (rbase & 1023) + quad * 4;
#pragma unroll
                for (int j = 0; j < NJ; ++j) {
                    const int vTrow = bb * 1024 + (col0 + wc + j * 16 + m16 - 2048);
                    *(uint2*)(vT + (size_t)vTrow * 1024 + tok0) =
                        make_uint2(pkbf(acc[i][j][0], acc[i][j][1]),
                                   pkbf(acc[i][j][2], acc[i][j][3]));
                }
            }
        }
    }
}

// ---------------------------------------------------------------- based attention
// Triangular pairing: block p handles q-tiles tA=p and tB=15-p (64 rows each)
// => every block does exactly 17 tile-units, one k/v staging serves both tiles.
// k/v double-buffered, ONE __syncthreads per kt-iter (prefetch for kt+1 issued
// right after the barrier). Units A and B processed JOINTLY per iteration:
// ks/vs fragments loaded once and shared; separate SsA/SsB buffers so the two
// units form independent MFMA streams (no false LDS dependency).
__global__ __launch_bounds__(256) void based_attn(const u16* __restrict__ qkm,
                                                  const u16* __restrict__ vT,
                                                  u16* __restrict__ o) {
    __shared__ u16 qsA[2][64][32];      // [dblk][qrow][32]
    __shared__ u16 qsB[2][64][32];
    __shared__ u16 ks[2][2][64][32];    // [buf][dblk][key][32]
    __shared__ u16 vs[2][2][64][32];    // [buf][kb][vdim][32 keys]
    __shared__ u16 SsA[2][64][32];      // [kb][qrow][32 keys] (wave-private rows)
    __shared__ u16 SsB[2][64][32];

    const int t = threadIdx.x, w = t >> 6, lane = t & 63;
    const int quad = lane >> 4, m16 = lane & 15;
    const int p = blockIdx.x, h = blockIdx.y, b = blockIdx.z;
    const int tA = p, tB = 15 - p;
    const int srow = lane >> 2, s8 = (lane & 3) * 8;

    const size_t qbase = (size_t)b * 1024 * 2048 + h * 64;
    const size_t kbase = qbase + 1024;
    const size_t vbase = ((size_t)b * 1024 + h * 64) * 1024;

    // prologue: q tiles A and B (8 chunks each); wave w takes chunks w*4+cc
#pragma unroll
    for (int cc = 0; cc < 4; ++cc) {
        const int c = w * 4 + cc;
        const int tile = c >> 3, dblk = (c >> 2) & 1, rc = c & 3;
        const int Q0 = (tile ? tB : tA) * 64;
        gll16(qkm + qbase + (size_t)(Q0 + rc * 16 + srow) * 2048 + dblk * 32 + s8,
              tile ? &qsB[dblk][rc * 16][0] : &qsA[dblk][rc * 16][0]);
    }
    // prologue: k/v tile kt=0 into buf 0; wave w takes chunks 2w,2w+1
#pragma unroll
    for (int cc = 0; cc < 2; ++cc) {
        const int c = w * 2 + cc;
        const int blk = c >> 2, rc = c & 3;
        gll16(qkm + kbase + (size_t)(rc * 16 + srow) * 2048 + blk * 32 + s8,
              &ks[0][blk][rc * 16][0]);
        gll16(vT + vbase + (size_t)(rc * 16 + srow) * 1024 + blk * 32 + s8,
              &vs[0][blk][rc * 16][0]);
    }

    bf16x8 ones;
#pragma unroll
    for (int e = 0; e < 8; ++e) ones[e] = (short)0x3F80;

    f32x4 numA[4], numB[4], denA, denB;
    denA = denB = (f32x4){0.f, 0.f, 0.f, 0.f};
#pragma unroll
    for (int j = 0; j < 4; ++j) numA[j] = numB[j] = (f32x4){0.f, 0.f, 0.f, 0.f};

    const int qrow = w * 16 + m16;       // this lane's q-row (local to tile)

    for (int kt = 0; kt <= tB; ++kt) {
        const int buf = kt & 1;
        __syncthreads();                 // loads for kt landed; buf^1 free to refill
        if (kt < tB) {
            const int nb = buf ^ 1, kn = kt + 1;
#pragma unroll
            for (int cc = 0; cc < 2; ++cc) {
                const int c = w * 2 + cc;
                const int blk = c >> 2, rc = c & 3;
                gll16(qkm + kbase + (size_t)(kn * 64 + rc * 16 + srow) * 2048 + blk * 32 + s8,
                      &ks[nb][blk][rc * 16][0]);
                gll16(vT + vbase + (size_t)(rc * 16 + srow) * 1024 + kn * 64 + blk * 32 + s8,
                      &vs[nb][blk][rc * 16][0]);
            }
        }
        const bool doA = (kt <= tA);

        // Phase 1 (both units, shared K-frags): S^T = K * Q^T
        f32x4 sA[4], sB[4];
#pragma unroll
        for (int jk = 0; jk < 4; ++jk)
            sA[jk] = sB[jk] = (f32x4){0.f, 0.f, 0.f, 0.f};
#pragma unroll
        for (int kd = 0; kd < 2; ++kd) {
            bf16x8 qfB = *(const bf16x8*)&qsB[kd][qrow][quad * 8];
            bf16x8 qfA = *(const bf16x8*)&qsA[kd][qrow][quad * 8];
#pragma unroll
            for (int jk = 0; jk < 4; ++jk) {
                bf16x8 af = *(const bf16x8*)&ks[buf][kd][jk * 16 + m16][quad * 8];
                sB[jk] = MFMA16(af, qfB, sB[jk]);
                if (doA) sA[jk] = MFMA16(af, qfA, sA[jk]);
            }
        }
        // transform: sc = 0.5*(s+1)^2 + 0.5, s = dot/8; mask only on diag tiles
#pragma unroll
        for (int jk = 0; jk < 4; ++jk) {
            const int key0 = jk * 16 + quad * 4;
            const int kl = jk * 16 + quad * 4;
            float scB[4];
#pragma unroll
            for (int r = 0; r < 4; ++r) {
                const float u = fmaf(sB[jk][r], 0.125f, 1.0f);
                scB[r] = fmaf(u * 0.5f, u, 0.5f);
            }
            if (kt == tB) {
#pragma unroll
                for (int r = 0; r < 4; ++r)
                    if (key0 + r > qrow) scB[r] = 0.f;
            }
            *(uint2*)&SsB[kl >> 5][qrow][kl & 31] =
                make_uint2(pkbf(scB[0], scB[1]), pkbf(scB[2], scB[3]));
            if (doA) {
                float scA[4];
#pragma unroll
                for (int r = 0; r < 4; ++r) {
                    const float u = fmaf(sA[jk][r], 0.125f, 1.0f);
                    scA[r] = fmaf(u * 0.5f, u, 0.5f);
                }
                if (kt == tA) {
#pragma unroll
                    for (int r = 0; r < 4; ++r)
                        if (key0 + r > qrow) scA[r] = 0.f;
                }
                *(uint2*)&SsA[kl >> 5][qrow][kl & 31] =
                    make_uint2(pkbf(scA[0], scA[1]), pkbf(scA[2], scA[3]));
            }
        }
        // Phase 2 (both units, shared V-frags); Ss rows wave-private -> no barrier
#pragma unroll
        for (int kb = 0; kb < 2; ++kb) {
            bf16x8 vf[4];
#pragma unroll
            for (int j = 0; j < 4; ++j)
                vf[j] = *(const bf16x8*)&vs[buf][kb][j * 16 + m16][quad * 8];
            bf16x8 sfB = *(const bf16x8*)&SsB[kb][qrow][quad * 8];
#pragma unroll
            for (int j = 0; j < 4; ++j) numB[j] = MFMA16(sfB, vf[j], numB[j]);
            denB = MFMA16(sfB, ones, denB);
            if (doA) {
                bf16x8 sfA = *(const bf16x8*)&SsA[kb][qrow][quad * 8];
#pragma unroll
                for (int j = 0; j < 4; ++j) numA[j] = MFMA16(sfA, vf[j], numA[j]);
                denA = MFMA16(sfA, ones, denA);
            }
        }
    }

    // epilogue: o[token][h*64+vdim] = num/den (bf16)
#pragma unroll
    for (int r = 0; r < 4; ++r) {
        const float invA = 1.0f / denA[r], invB = 1.0f / denB[r];
        const int rowoff = w * 16 + quad * 4 + r;
        const size_t tokA = (size_t)(b * 1024 + tA * 64 + rowoff);
        const size_t tokB = (size_t)(b * 1024 + tB * 64 + rowoff);
#pragma unroll
        for (int j = 0; j < 4; ++j) {
            o[tokA * 1024 + h * 64 + j * 16 + m16] = f2b(numA[j][r] * invA);
            o[tokB * 1024 + h * 64 + j * 16 + m16] = f2b(numB[j][r] * invB);
        }
    }
}

// ---------------------------------------------------------------- launch
extern "C" void kernel_launch(void* const* d_in, const int* in_sizes, int n_in,
                              void* d_out, int out_size, void* d_ws, size_t ws_size,
                              hipStream_t stream) {
    const float* x  = (const float*)d_in[0];
    const float* Wq = (const float*)d_in[1];
    const float* Wk = (const float*)d_in[2];
    const float* Wv = (const float*)d_in[3];
    const float* Wo = (const float*)d_in[4];
    float* out = (float*)d_out;

    const size_t MEL = 4096ull * 1024ull;        // 4M elements
    u16* xb   = (u16*)d_ws;                      // 4096 x 1024
    u16* Wqkv = xb + MEL;                        // 3072 x 1024 (Wq|Wk|Wv rows)
    u16* Wob  = Wqkv + 3ull * 1024 * 1024;       // 1024 x 1024 (contiguous after)
    u16* qk   = Wob + 1024ull * 1024;            // 4096 x 2048 (q|k)
    u16* vT   = qk + 2ull * MEL;                 // [b*1024+h*64+vd][1024 tokens]
    u16* o    = vT + MEL;                        // 4096 x 1024

    cast_all<<<4096, 256, 0, stream>>>(x, Wq, Wk, Wv, Wo, xb, Wqkv);

    dim3 gq(32, 24);   // 4096/128 x 3072/128; y>=16 blocks write vT directly
    gemm_bt<128, 128, 1><<<gq, 256, 0, stream>>>(xb, Wqkv, qk, vT, 1024, 2048);

    dim3 ga(8, 16, 4); // pair index x heads x batch — uniform work per block
    based_attn<<<ga, 256, 0, stream>>>(qk, vT, o);

    dim3 go(64, 16);   // 64x64 tiles -> 1024 blocks, 4/CU, dbuf 16KB LDS
    gemm_bt<64, 64, 0><<<go, 256, 0, stream>>>(o, Wob, (void*)out, nullptr, 1024, 1024);
}